// Round 1
// baseline (785.475 us; speedup 1.0000x reference)
//
#include <hip/hip_runtime.h>
#include <stdint.h>

// ---------------------------------------------------------------------------
// GCastHeterocoder: edge MLP (gather+GEMM K=384) -> scatter-sum -> node MLP
// (K=256) -> sender MLP (K=128). GEMMs in bf16 MFMA (16x16x32), fp32 accum.
// d_ws usage: bf16 copies of We/Wn/Ws (196608 B). Aggregation accumulates
// into the receiver_out region of d_out (memset to 0 each call).
// ---------------------------------------------------------------------------

typedef __bf16 bf16x8 __attribute__((ext_vector_type(8)));
typedef float  f32x4  __attribute__((ext_vector_type(4)));

union U16B { uint4 u; bf16x8 v; };

__device__ __forceinline__ unsigned short f2bf(float f) {
  unsigned int u = __float_as_uint(f);
  unsigned int r = (u + 0x7fffu + ((u >> 16) & 1u)) >> 16;  // RNE
  return (unsigned short)r;
}
__device__ __forceinline__ unsigned int pk2(float a, float b) {
  return (unsigned int)f2bf(a) | ((unsigned int)f2bf(b) << 16);
}
__device__ __forceinline__ float silu_f(float x) {
  return x / (1.0f + __expf(-x));
}

// fp32 -> bf16 weight conversion into workspace (once per launch, ~3us)
__global__ void cvt_weights_kernel(const float* __restrict__ We,
                                   const float* __restrict__ Wn,
                                   const float* __restrict__ Ws,
                                   unsigned short* __restrict__ out) {
  const int nWe = 128 * 384, nWn = 128 * 256, nWs = 128 * 128;
  int i = blockIdx.x * 256 + threadIdx.x;
  if (i < nWe) out[i] = f2bf(We[i]);
  else if (i < nWe + nWn) out[i] = f2bf(Wn[i - nWe]);
  else if (i < nWe + nWn + nWs) out[i] = f2bf(Ws[i - nWe - nWn]);
}

// ---------------------------------------------------------------------------
// Fused GCastMLP: out[r] = resid[r] + LN(silu(silu(in[r] @ W^T + b)))*g + bb
// in[r] = concat of up to 3 segments of 128 fp32 each (optionally gathered).
// Optionally scatter-adds the MLP output (pre-residual) to aggr[aggr_idx[r]].
// Block: 256 thr (4 waves), 128 rows/block; wave w owns rows w*32..w*32+31,
// all 128 output channels (LN stays within a 16-lane group).
// ---------------------------------------------------------------------------
template <int KDIM, bool HAS_AGGR>
__global__ __launch_bounds__(256) void mlp_fused_kernel(
    const float* __restrict__ s0, const int* __restrict__ i0,
    const float* __restrict__ s1, const int* __restrict__ i1,
    const float* __restrict__ s2,
    const unsigned short* __restrict__ Wb,   // [128][KDIM] bf16 row-major
    const float* __restrict__ bias, const float* __restrict__ gamma,
    const float* __restrict__ beta,
    const float* __restrict__ resid,
    float* __restrict__ outp,
    float* aggr, const int* __restrict__ aggr_idx,
    int M) {
  constexpr int BM = 128, BK = 64, LDW = 72;  // 72*2B=144B row stride: 16B-aligned, bank-rotating
  __shared__ __align__(16) unsigned short Ash[BM * LDW];
  __shared__ __align__(16) unsigned short Bsh[128 * LDW];

  const int tid = threadIdx.x;
  const int brow0 = blockIdx.x * BM;

  // staging assignment: 2 threads per row, 32 cols each
  const int srow = tid >> 1;
  const int shalf = tid & 1;
  const int grow_s = brow0 + srow;
  const int crow = grow_s < M ? grow_s : (M - 1);  // clamp tail (stores masked)

  const float* rp0 = s0 + (size_t)(i0 ? i0[crow] : crow) * 128;
  const float* rp1 = (KDIM >= 256) ? (s1 + (size_t)(i1 ? i1[crow] : crow) * 128) : nullptr;
  const float* rp2 = (KDIM >= 384) ? (s2 + (size_t)crow * 128) : nullptr;

  const int wid = tid >> 6;
  const int lane = tid & 63;
  const int l15 = lane & 15;
  const int q = lane >> 4;

  const int a_base = (wid * 32 + l15) * LDW + q * 8;
  const int b_base = l15 * LDW + q * 8;

  f32x4 acc[2][8] = {};  // zero-init: 2 row-tiles x 8 channel-tiles

  for (int kc = 0; kc < KDIM; kc += BK) {
    // ---- stage A (gather fp32 rows, convert to bf16) ----
    {
      const float* srcrow = (kc < 128) ? rp0 : ((KDIM >= 384 && kc >= 256) ? rp2 : rp1);
      const float* src = srcrow + (kc & 127) + shalf * 32;
      unsigned short* dst = &Ash[srow * LDW + shalf * 32];
      #pragma unroll
      for (int u = 0; u < 4; ++u) {
        float4 a = reinterpret_cast<const float4*>(src)[2 * u];
        float4 b = reinterpret_cast<const float4*>(src)[2 * u + 1];
        uint4 w;
        w.x = pk2(a.x, a.y); w.y = pk2(a.z, a.w);
        w.z = pk2(b.x, b.y); w.w = pk2(b.z, b.w);
        *reinterpret_cast<uint4*>(&dst[u * 8]) = w;
      }
    }
    // ---- stage B (bf16 weights, straight copy) ----
    {
      const unsigned short* src = Wb + (size_t)srow * KDIM + kc + shalf * 32;
      unsigned short* dst = &Bsh[srow * LDW + shalf * 32];
      #pragma unroll
      for (int u = 0; u < 4; ++u)
        *reinterpret_cast<uint4*>(&dst[u * 8]) = reinterpret_cast<const uint4*>(src)[u];
    }
    __syncthreads();
    // ---- MFMA: 2 K-steps of 32, 2 M-tiles x 8 N-tiles ----
    #pragma unroll
    for (int kk = 0; kk < BK; kk += 32) {
      U16B a0, a1;
      a0.u = *reinterpret_cast<const uint4*>(&Ash[a_base + kk]);
      a1.u = *reinterpret_cast<const uint4*>(&Ash[a_base + 16 * LDW + kk]);
      #pragma unroll
      for (int n = 0; n < 8; ++n) {
        U16B bb;
        bb.u = *reinterpret_cast<const uint4*>(&Bsh[b_base + n * 16 * LDW + kk]);
        acc[0][n] = __builtin_amdgcn_mfma_f32_16x16x32_bf16(a0.v, bb.v, acc[0][n], 0, 0, 0);
        acc[1][n] = __builtin_amdgcn_mfma_f32_16x16x32_bf16(a1.v, bb.v, acc[1][n], 0, 0, 0);
      }
    }
    __syncthreads();
  }

  // ---- epilogue: bias, silu(silu(.)), LayerNorm, residual, scatter ----
  float bia[8], gam[8], bet[8];
  #pragma unroll
  for (int n = 0; n < 8; ++n) {
    int ch = n * 16 + l15;
    bia[n] = bias[ch]; gam[n] = gamma[ch]; bet[n] = beta[ch];
  }

  #pragma unroll
  for (int mt = 0; mt < 2; ++mt) {
    float v[8][4];
    float sum[4] = {0.f, 0.f, 0.f, 0.f};
    float ssq[4] = {0.f, 0.f, 0.f, 0.f};
    #pragma unroll
    for (int n = 0; n < 8; ++n) {
      #pragma unroll
      for (int j = 0; j < 4; ++j) {
        float z = acc[mt][n][j] + bia[n];
        float t = silu_f(silu_f(z));
        v[n][j] = t;
        sum[j] += t;
        ssq[j] += t * t;
      }
    }
    // reduce over the 16-lane group (channels of each row)
    #pragma unroll
    for (int off = 1; off < 16; off <<= 1) {
      #pragma unroll
      for (int j = 0; j < 4; ++j) {
        sum[j] += __shfl_xor(sum[j], off);
        ssq[j] += __shfl_xor(ssq[j], off);
      }
    }
    #pragma unroll
    for (int j = 0; j < 4; ++j) {
      float mu = sum[j] * (1.0f / 128.0f);
      float var = ssq[j] * (1.0f / 128.0f) - mu * mu;
      float rs = rsqrtf(var + 1e-5f);
      int grow = brow0 + wid * 32 + mt * 16 + q * 4 + j;
      if (grow < M) {
        const float* rrow = resid + (size_t)grow * 128;
        float* orow = outp + (size_t)grow * 128;
        float* arow = nullptr;
        if (HAS_AGGR) arow = aggr + (size_t)aggr_idx[grow] * 128;
        #pragma unroll
        for (int n = 0; n < 8; ++n) {
          int ch = n * 16 + l15;
          float y = (v[n][j] - mu) * rs * gam[n] + bet[n];
          orow[ch] = rrow[ch] + y;
          if (HAS_AGGR) atomicAdd(&arow[ch], y);
        }
      }
    }
  }
}

extern "C" void kernel_launch(void* const* d_in, const int* in_sizes, int n_in,
                              void* d_out, int out_size, void* d_ws, size_t ws_size,
                              hipStream_t stream) {
  const float* sender_x   = (const float*)d_in[0];
  const float* receiver_x = (const float*)d_in[1];
  const int*   edge_index = (const int*)d_in[2];
  const float* edge_attr  = (const float*)d_in[3];
  const float* We  = (const float*)d_in[4];
  const float* be  = (const float*)d_in[5];
  const float* ge  = (const float*)d_in[6];
  const float* bbe = (const float*)d_in[7];
  const float* Wn  = (const float*)d_in[8];
  const float* bn  = (const float*)d_in[9];
  const float* gn  = (const float*)d_in[10];
  const float* bbn = (const float*)d_in[11];
  const float* Ws  = (const float*)d_in[12];
  const float* bs  = (const float*)d_in[13];
  const float* gs  = (const float*)d_in[14];
  const float* bbs = (const float*)d_in[15];

  const int D  = 128;
  const int NS = in_sizes[0] / D;
  const int NR = in_sizes[1] / D;
  const int E  = in_sizes[2] / 2;

  const int* src = edge_index;
  const int* dst = edge_index + E;

  float* out          = (float*)d_out;
  float* sender_out   = out;
  float* receiver_out = out + (size_t)NS * D;   // doubles as edge_aggr accumulator
  float* edge_out     = out + (size_t)(NS + NR) * D;

  unsigned short* We_b = (unsigned short*)d_ws;          // 128*384
  unsigned short* Wn_b = We_b + 128 * 384;               // 128*256
  unsigned short* Ws_b = Wn_b + 128 * 256;               // 128*128

  const int totalW = 128 * 384 + 128 * 256 + 128 * 128;
  cvt_weights_kernel<<<(totalW + 255) / 256, 256, 0, stream>>>(We, Wn, Ws, We_b);

  hipMemsetAsync(receiver_out, 0, (size_t)NR * D * sizeof(float), stream);

  // 1) Edge MLP: concat(sender_x[src], receiver_x[dst], edge_attr) -> p
  //    edge_out = edge_attr + p ; aggr[dst] += p
  mlp_fused_kernel<384, true><<<(E + 127) / 128, 256, 0, stream>>>(
      sender_x, src, receiver_x, dst, edge_attr,
      We_b, be, ge, bbe,
      edge_attr, edge_out,
      receiver_out, dst, E);

  // 2) Node MLP: concat(receiver_x, aggr) -> mesh_x_p ; receiver_out = receiver_x + mesh_x_p
  mlp_fused_kernel<256, false><<<(NR + 127) / 128, 256, 0, stream>>>(
      receiver_x, nullptr, receiver_out, nullptr, nullptr,
      Wn_b, bn, gn, bbn,
      receiver_x, receiver_out,
      nullptr, nullptr, NR);

  // 3) Sender MLP: sender_out = sender_x + MLP(sender_x)
  mlp_fused_kernel<128, false><<<(NS + 127) / 128, 256, 0, stream>>>(
      sender_x, nullptr, nullptr, nullptr, nullptr,
      Ws_b, bs, gs, bbs,
      sender_x, sender_out,
      nullptr, nullptr, NS);
}

// Round 2
// 764.936 us; speedup vs baseline: 1.0269x; 1.0269x over previous
//
#include <hip/hip_runtime.h>
#include <stdint.h>

// ---------------------------------------------------------------------------
// GCastHeterocoder round 2: barrier-free, LDS-free register-fragment MFMA MLP.
//  - A fragments loaded per-lane directly from global (gathered rows), native
//    bf16 casts. B fragments read directly from global (L2-resident 96 KB).
//  - Scatter-sum via packed bf16 atomics (global_atomic_pk_add_bf16) into a
//    bf16 aggregate buffer in d_ws (fp32 atomicAdd fallback if ws too small).
// ---------------------------------------------------------------------------

typedef __bf16 bf16x8 __attribute__((ext_vector_type(8)));
typedef float  f32x4  __attribute__((ext_vector_type(4)));

union U16B { uint4 u; bf16x8 v; };
union BFPK { __bf16 h[2]; unsigned int u; };
union BF1  { __bf16 h; unsigned short s; };

__device__ __forceinline__ float silu_f(float x) { return x / (1.0f + __expf(-x)); }

__device__ __forceinline__ bf16x8 cvt8(float4 a, float4 b) {
  bf16x8 r;
  r[0] = (__bf16)a.x; r[1] = (__bf16)a.y; r[2] = (__bf16)a.z; r[3] = (__bf16)a.w;
  r[4] = (__bf16)b.x; r[5] = (__bf16)b.y; r[6] = (__bf16)b.z; r[7] = (__bf16)b.w;
  return r;
}

// fp32 -> bf16 weight conversion into workspace (once per launch)
__global__ void cvt_weights_kernel(const float* __restrict__ We,
                                   const float* __restrict__ Wn,
                                   const float* __restrict__ Ws,
                                   unsigned short* __restrict__ out) {
  const int nWe = 128 * 384, nWn = 128 * 256, nWs = 128 * 128;
  int i = blockIdx.x * 256 + threadIdx.x;
  float f;
  if (i < nWe) f = We[i];
  else if (i < nWe + nWn) f = Wn[i - nWe];
  else if (i < nWe + nWn + nWs) f = Ws[i - nWe - nWn];
  else return;
  BF1 c; c.h = (__bf16)f;
  out[i] = c.s;
}

// ---------------------------------------------------------------------------
// Fused GCastMLP: out[r] = resid[r] + LN(silu(silu(in[r] @ W^T + b)))*g + bb
// in[r] = concat of up to 3 segments of 128 each (seg0/seg1 optionally
// gathered; seg1 may be bf16). AGGR: 0=none, 1=fp32 atomicAdd, 2=pk bf16.
// Block: 256 thr (4 waves), 128 rows/block; wave owns 32 rows x 128 ch.
// No LDS, no barriers: pure register MFMA, loads direct from global.
// ---------------------------------------------------------------------------
template <int KDIM, int AGGR, bool SEG1_BF16>
__global__ __launch_bounds__(256, 3) void mlp_rf_kernel(
    const float* __restrict__ s0, const int* __restrict__ i0,
    const void*  __restrict__ s1v, const int* __restrict__ i1,
    const float* __restrict__ s2,
    const unsigned short* __restrict__ Wb,   // [128][KDIM] bf16 row-major
    const float* __restrict__ bias, const float* __restrict__ gamma,
    const float* __restrict__ beta,
    const float* __restrict__ resid,
    float* __restrict__ outp,
    void* aggr, const int* __restrict__ aggr_idx,
    int M) {
  const int tid = threadIdx.x;
  const int wid = tid >> 6;
  const int lane = tid & 63;
  const int l15 = lane & 15;
  const int q = lane >> 4;
  const int wrow0 = blockIdx.x * 128 + wid * 32;

  // A source row pointers for the 2 m-tiles this lane loads (row = wrow0+mt*16+l15)
  const float* pS0[2];
  const float* pS1f[2];
  const unsigned short* pS1b[2];
  const float* pS2[2];
  #pragma unroll
  for (int mt = 0; mt < 2; ++mt) {
    int r = wrow0 + mt * 16 + l15;
    if (r >= M) r = M - 1;  // clamp tail; stores are masked
    pS0[mt] = s0 + (size_t)(i0 ? i0[r] : r) * 128;
    if (KDIM >= 256) {
      int r1 = i1 ? i1[r] : r;
      pS1f[mt] = (const float*)s1v + (size_t)r1 * 128;
      pS1b[mt] = (const unsigned short*)s1v + (size_t)r1 * 128;
    }
    if (KDIM >= 384) pS2[mt] = s2 + (size_t)r * 128;
  }

  f32x4 acc[2][8] = {};

  #pragma unroll
  for (int ks = 0; ks < KDIM / 32; ++ks) {
    const int seg = ks >> 2;                 // which 128-col segment
    const int kof = (ks & 3) * 32 + q * 8;   // element offset within segment
    U16B a[2];
    #pragma unroll
    for (int mt = 0; mt < 2; ++mt) {
      if (seg == 1 && SEG1_BF16) {
        a[mt].u = *reinterpret_cast<const uint4*>(pS1b[mt] + kof);
      } else {
        const float* base = (seg == 0) ? pS0[mt] : ((seg == 1) ? pS1f[mt] : pS2[mt]);
        const float4* p = reinterpret_cast<const float4*>(base + kof);
        a[mt].v = cvt8(p[0], p[1]);
      }
    }
    #pragma unroll
    for (int n = 0; n < 8; ++n) {
      U16B b;
      b.u = *reinterpret_cast<const uint4*>(Wb + (size_t)(n * 16 + l15) * KDIM + ks * 32 + q * 8);
      acc[0][n] = __builtin_amdgcn_mfma_f32_16x16x32_bf16(a[0].v, b.v, acc[0][n], 0, 0, 0);
      acc[1][n] = __builtin_amdgcn_mfma_f32_16x16x32_bf16(a[1].v, b.v, acc[1][n], 0, 0, 0);
    }
  }

  // ---- epilogue: bias, silu(silu(.)), LayerNorm, residual, scatter ----
  float bia[8], gam[8], bet[8];
  #pragma unroll
  for (int n = 0; n < 8; ++n) {
    int ch = n * 16 + l15;
    bia[n] = bias[ch]; gam[n] = gamma[ch]; bet[n] = beta[ch];
  }

  #pragma unroll
  for (int mt = 0; mt < 2; ++mt) {
    float v[8][4];
    float sum[4] = {0.f, 0.f, 0.f, 0.f};
    float ssq[4] = {0.f, 0.f, 0.f, 0.f};
    #pragma unroll
    for (int n = 0; n < 8; ++n) {
      #pragma unroll
      for (int j = 0; j < 4; ++j) {
        float t = silu_f(silu_f(acc[mt][n][j] + bia[n]));
        v[n][j] = t;
        sum[j] += t;
        ssq[j] += t * t;
      }
    }
    // reduce across the 16-lane group (channels of each row)
    #pragma unroll
    for (int off = 1; off < 16; off <<= 1) {
      #pragma unroll
      for (int j = 0; j < 4; ++j) {
        sum[j] += __shfl_xor(sum[j], off);
        ssq[j] += __shfl_xor(ssq[j], off);
      }
    }
    #pragma unroll
    for (int j = 0; j < 4; ++j) {
      float mu = sum[j] * (1.0f / 128.0f);
      float var = ssq[j] * (1.0f / 128.0f) - mu * mu;
      float rs = rsqrtf(var + 1e-5f);
      int grow = wrow0 + mt * 16 + q * 4 + j;
      if (grow < M) {
        const float* rrow = resid + (size_t)grow * 128;
        float* orow = outp + (size_t)grow * 128;
        float ya[8];
        #pragma unroll
        for (int n = 0; n < 8; ++n) {
          float y = (v[n][j] - mu) * rs * gam[n] + bet[n];
          ya[n] = y;
          orow[n * 16 + l15] = rrow[n * 16 + l15] + y;
        }
        if (AGGR == 1) {
          float* arow = (float*)aggr + (size_t)aggr_idx[grow] * 128;
          #pragma unroll
          for (int n = 0; n < 8; ++n) atomicAdd(&arow[n * 16 + l15], ya[n]);
        } else if (AGGR == 2) {
          unsigned short* arow = (unsigned short*)aggr + (size_t)aggr_idx[grow] * 128;
          #pragma unroll
          for (int n = 0; n < 8; ++n) {
            float t = __shfl_xor(ya[n], 1);  // partner channel (same q, l15^1)
            if (!(l15 & 1)) {
              BFPK pk;
              pk.h[0] = (__bf16)ya[n];  // ch (even)
              pk.h[1] = (__bf16)t;      // ch+1
              unsigned short* p = arow + n * 16 + l15;
              asm volatile("global_atomic_pk_add_bf16 %0, %1, off"
                           :: "v"(p), "v"(pk.u) : "memory");
            }
          }
        }
      }
    }
  }
}

extern "C" void kernel_launch(void* const* d_in, const int* in_sizes, int n_in,
                              void* d_out, int out_size, void* d_ws, size_t ws_size,
                              hipStream_t stream) {
  const float* sender_x   = (const float*)d_in[0];
  const float* receiver_x = (const float*)d_in[1];
  const int*   edge_index = (const int*)d_in[2];
  const float* edge_attr  = (const float*)d_in[3];
  const float* We  = (const float*)d_in[4];
  const float* be  = (const float*)d_in[5];
  const float* ge  = (const float*)d_in[6];
  const float* bbe = (const float*)d_in[7];
  const float* Wn  = (const float*)d_in[8];
  const float* bn  = (const float*)d_in[9];
  const float* gn  = (const float*)d_in[10];
  const float* bbn = (const float*)d_in[11];
  const float* Ws  = (const float*)d_in[12];
  const float* bs  = (const float*)d_in[13];
  const float* gs  = (const float*)d_in[14];
  const float* bbs = (const float*)d_in[15];

  const int D  = 128;
  const int NS = in_sizes[0] / D;
  const int NR = in_sizes[1] / D;
  const int E  = in_sizes[2] / 2;

  const int* src = edge_index;
  const int* dst = edge_index + E;

  float* out          = (float*)d_out;
  float* sender_out   = out;
  float* receiver_out = out + (size_t)NS * D;
  float* edge_out     = out + (size_t)(NS + NR) * D;

  unsigned short* We_b = (unsigned short*)d_ws;          // 128*384
  unsigned short* Wn_b = We_b + 128 * 384;               // 128*256
  unsigned short* Ws_b = Wn_b + 128 * 256;               // 128*128
  unsigned short* aggr_b = Ws_b + 128 * 128;             // NR*128 bf16

  const size_t wel = 128 * 384 + 128 * 256 + 128 * 128;  // weight elements
  const size_t need = wel * 2 + (size_t)NR * D * 2;
  const bool bf16aggr = (ws_size >= need);

  cvt_weights_kernel<<<(int)((wel + 255) / 256), 256, 0, stream>>>(We, Wn, Ws, We_b);

  if (bf16aggr) {
    hipMemsetAsync(aggr_b, 0, (size_t)NR * D * 2, stream);
    // 1) Edge MLP + residual + pk-bf16 scatter into aggr_b
    mlp_rf_kernel<384, 2, false><<<(E + 127) / 128, 256, 0, stream>>>(
        sender_x, src, receiver_x, dst, edge_attr,
        We_b, be, ge, bbe,
        edge_attr, edge_out,
        aggr_b, dst, E);
    // 2) Node MLP: concat(receiver_x fp32, aggr bf16)
    mlp_rf_kernel<256, 0, true><<<(NR + 127) / 128, 256, 0, stream>>>(
        receiver_x, nullptr, aggr_b, nullptr, nullptr,
        Wn_b, bn, gn, bbn,
        receiver_x, receiver_out,
        nullptr, nullptr, NR);
  } else {
    hipMemsetAsync(receiver_out, 0, (size_t)NR * D * sizeof(float), stream);
    mlp_rf_kernel<384, 1, false><<<(E + 127) / 128, 256, 0, stream>>>(
        sender_x, src, receiver_x, dst, edge_attr,
        We_b, be, ge, bbe,
        edge_attr, edge_out,
        receiver_out, dst, E);
    mlp_rf_kernel<256, 0, false><<<(NR + 127) / 128, 256, 0, stream>>>(
        receiver_x, nullptr, receiver_out, nullptr, nullptr,
        Wn_b, bn, gn, bbn,
        receiver_x, receiver_out,
        nullptr, nullptr, NR);
  }

  // 3) Sender MLP
  mlp_rf_kernel<128, 0, false><<<(NS + 127) / 128, 256, 0, stream>>>(
      sender_x, nullptr, nullptr, nullptr, nullptr,
      Ws_b, bs, gs, bbs,
      sender_x, sender_out,
      nullptr, nullptr, NS);
}

// Round 4
// 659.012 us; speedup vs baseline: 1.1919x; 1.1607x over previous
//
#include <hip/hip_runtime.h>
#include <stdint.h>

// ---------------------------------------------------------------------------
// GCastHeterocoder round 3b: register-fragment MFMA MLP, bf16 node features,
// LDS epilogue transpose -> coalesced nt float4 stores + batched pk-bf16
// atomics on contiguous 256B aggregate rows. (Fixes nontemporal_store type.)
// ws tiers: A = bf16 weights + bf16 sender/receiver + bf16 aggr (~77 MB)
//           B = bf16 weights + bf16 aggr (~26 MB)
//           C = bf16 weights only, fp32 atomics into receiver_out
// ---------------------------------------------------------------------------

typedef __bf16 bf16x8 __attribute__((ext_vector_type(8)));
typedef float  f32x4  __attribute__((ext_vector_type(4)));

union U16B { uint4 u; bf16x8 v; };
union BFPK { __bf16 h[2]; unsigned int u; };
union BF1  { __bf16 h; unsigned short s; };

__device__ __forceinline__ float silu_f(float x) {
  return x * __builtin_amdgcn_rcpf(1.0f + __expf(-x));
}

__device__ __forceinline__ bf16x8 cvt8(float4 a, float4 b) {
  bf16x8 r;
  r[0] = (__bf16)a.x; r[1] = (__bf16)a.y; r[2] = (__bf16)a.z; r[3] = (__bf16)a.w;
  r[4] = (__bf16)b.x; r[5] = (__bf16)b.y; r[6] = (__bf16)b.z; r[7] = (__bf16)b.w;
  return r;
}

// scalar weight conversion (98304 elements, trivial)
__global__ void cvt_weights_kernel(const float* __restrict__ We,
                                   const float* __restrict__ Wn,
                                   const float* __restrict__ Ws,
                                   unsigned short* __restrict__ out) {
  const int nWe = 128 * 384, nWn = 128 * 256, nWs = 128 * 128;
  int i = blockIdx.x * 256 + threadIdx.x;
  float f;
  if (i < nWe) f = We[i];
  else if (i < nWe + nWn) f = Wn[i - nWe];
  else if (i < nWe + nWn + nWs) f = Ws[i - nWe - nWn];
  else return;
  BF1 c; c.h = (__bf16)f;
  out[i] = c.s;
}

// vectorized fp32 -> bf16 row conversion (8 elements/thread)
__global__ void cvt_rows_kernel(const float* __restrict__ in,
                                unsigned short* __restrict__ out, int n8) {
  int i = blockIdx.x * 256 + threadIdx.x;
  if (i >= n8) return;
  float4 a = reinterpret_cast<const float4*>(in)[2 * i];
  float4 b = reinterpret_cast<const float4*>(in)[2 * i + 1];
  U16B r; r.v = cvt8(a, b);
  reinterpret_cast<uint4*>(out)[i] = r.u;
}

// ---------------------------------------------------------------------------
// Fused GCastMLP. AGGR: 0=none, 1=fp32 atomicAdd, 2=pk bf16 atomics.
// S0B/S1B: segment 0/1 stored as bf16. Segment 2 always fp32 (edge_attr).
// 256 thr / 4 waves, 128 rows per block, wave owns 32 rows x 128 ch.
// ---------------------------------------------------------------------------
template <int KDIM, int AGGR, bool S0B, bool S1B>
__global__ __launch_bounds__(256, 4) void mlp_rf2_kernel(
    const void* __restrict__ s0v, const int* __restrict__ i0,
    const void* __restrict__ s1v, const int* __restrict__ i1,
    const float* __restrict__ s2,
    const unsigned short* __restrict__ Wb,   // [128][KDIM] bf16 row-major
    const float* __restrict__ bias, const float* __restrict__ gamma,
    const float* __restrict__ beta,
    const float* __restrict__ resid,
    float* __restrict__ outp,
    void* aggr, const int* __restrict__ aggr_idx,
    int M) {
  __shared__ __align__(16) float yT[4][16][132];

  const int tid = threadIdx.x;
  const int wid = tid >> 6;
  const int lane = tid & 63;
  const int l15 = lane & 15;
  const int q = lane >> 4;
  const int l31 = lane & 31;
  const int rhalf = lane >> 5;
  const int wrow0 = blockIdx.x * 128 + wid * 32;

  // A row pointers for the 2 m-tiles (row = wrow0 + mt*16 + l15)
  const unsigned short* p0b[2]; const float* p0f[2];
  const unsigned short* p1b[2]; const float* p1f[2];
  const float* p2[2];
  #pragma unroll
  for (int mt = 0; mt < 2; ++mt) {
    int r = wrow0 + mt * 16 + l15;
    if (r >= M) r = M - 1;  // clamp tail; stores masked later
    int r0 = i0 ? i0[r] : r;
    if constexpr (S0B) p0b[mt] = (const unsigned short*)s0v + (size_t)r0 * 128;
    else               p0f[mt] = (const float*)s0v + (size_t)r0 * 128;
    if constexpr (KDIM >= 256) {
      int r1 = i1 ? i1[r] : r;
      if constexpr (S1B) p1b[mt] = (const unsigned short*)s1v + (size_t)r1 * 128;
      else               p1f[mt] = (const float*)s1v + (size_t)r1 * 128;
    }
    if constexpr (KDIM >= 384) p2[mt] = s2 + (size_t)r * 128;
  }

  f32x4 acc[2][8] = {};

  #pragma unroll
  for (int ks = 0; ks < KDIM / 32; ++ks) {
    const int seg = ks >> 2;
    const int kof = (ks & 3) * 32 + q * 8;
    U16B a[2];
    #pragma unroll
    for (int mt = 0; mt < 2; ++mt) {
      if (seg == 0) {
        if constexpr (S0B) {
          a[mt].u = *reinterpret_cast<const uint4*>(p0b[mt] + kof);
        } else {
          const float4* p = reinterpret_cast<const float4*>(p0f[mt] + kof);
          a[mt].v = cvt8(p[0], p[1]);
        }
      } else if (seg == 1) {
        if constexpr (S1B) {
          a[mt].u = *reinterpret_cast<const uint4*>(p1b[mt] + kof);
        } else {
          const float4* p = reinterpret_cast<const float4*>(p1f[mt] + kof);
          a[mt].v = cvt8(p[0], p[1]);
        }
      } else {
        const float4* p = reinterpret_cast<const float4*>(p2[mt] + kof);
        a[mt].v = cvt8(p[0], p[1]);
      }
    }
    #pragma unroll
    for (int n = 0; n < 8; ++n) {
      U16B b;
      b.u = *reinterpret_cast<const uint4*>(Wb + (size_t)(n * 16 + l15) * KDIM + ks * 32 + q * 8);
      acc[0][n] = __builtin_amdgcn_mfma_f32_16x16x32_bf16(a[0].v, b.v, acc[0][n], 0, 0, 0);
      acc[1][n] = __builtin_amdgcn_mfma_f32_16x16x32_bf16(a[1].v, b.v, acc[1][n], 0, 0, 0);
    }
  }

  // ---- epilogue ----
  float bia[8], gam[8], bet[8];
  #pragma unroll
  for (int n = 0; n < 8; ++n) {
    int ch = n * 16 + l15;
    bia[n] = bias[ch]; gam[n] = gamma[ch]; bet[n] = beta[ch];
  }

  #pragma unroll
  for (int mt = 0; mt < 2; ++mt) {
    float vv[8][4];
    float sum[4] = {0.f, 0.f, 0.f, 0.f};
    float ssq[4] = {0.f, 0.f, 0.f, 0.f};
    #pragma unroll
    for (int n = 0; n < 8; ++n) {
      #pragma unroll
      for (int j = 0; j < 4; ++j) {
        float t = silu_f(silu_f(acc[mt][n][j] + bia[n]));
        vv[n][j] = t;
        sum[j] += t;
        ssq[j] += t * t;
      }
    }
    #pragma unroll
    for (int off = 1; off < 16; off <<= 1) {
      #pragma unroll
      for (int j = 0; j < 4; ++j) {
        sum[j] += __shfl_xor(sum[j], off);
        ssq[j] += __shfl_xor(ssq[j], off);
      }
    }
    float mu[4], rs[4];
    #pragma unroll
    for (int j = 0; j < 4; ++j) {
      mu[j] = sum[j] * (1.0f / 128.0f);
      float var = ssq[j] * (1.0f / 128.0f) - mu[j] * mu[j];
      rs[j] = rsqrtf(var + 1e-5f);
    }

    if (mt == 1) {  // WAR guard: mt0 reads must complete before overwrite
      asm volatile("s_waitcnt lgkmcnt(0)" ::: "memory");
    }
    // transpose through LDS: y[row16 = q*4+j][ch = n*16+l15]
    #pragma unroll
    for (int n = 0; n < 8; ++n) {
      #pragma unroll
      for (int j = 0; j < 4; ++j) {
        float y = (vv[n][j] - mu[j]) * rs[j] * gam[n] + bet[n];
        yT[wid][q * 4 + j][n * 16 + l15] = y;
      }
    }
    asm volatile("s_waitcnt lgkmcnt(0)" ::: "memory");

    // coalesced store phase: 2 rows per pass, lane -> 4 contiguous channels
    #pragma unroll
    for (int s = 0; s < 8; ++s) {
      int row16 = 2 * s + rhalf;
      int grow = wrow0 + mt * 16 + row16;
      f32x4 y4 = *reinterpret_cast<const f32x4*>(&yT[wid][row16][l31 * 4]);
      if (grow < M) {
        const f32x4 r4 = *reinterpret_cast<const f32x4*>(resid + (size_t)grow * 128 + l31 * 4);
        f32x4 o4 = r4 + y4;
        __builtin_nontemporal_store(o4, reinterpret_cast<f32x4*>(outp + (size_t)grow * 128 + l31 * 4));
        if constexpr (AGGR == 2) {
          int idx = aggr_idx[grow];
          unsigned short* ar = (unsigned short*)aggr + (size_t)idx * 128 + l31 * 4;
          BFPK k0, k1;
          k0.h[0] = (__bf16)y4.x; k0.h[1] = (__bf16)y4.y;
          k1.h[0] = (__bf16)y4.z; k1.h[1] = (__bf16)y4.w;
          asm volatile("global_atomic_pk_add_bf16 %0, %1, off" :: "v"(ar), "v"(k0.u) : "memory");
          asm volatile("global_atomic_pk_add_bf16 %0, %1, off" :: "v"(ar + 2), "v"(k1.u) : "memory");
        } else if constexpr (AGGR == 1) {
          int idx = aggr_idx[grow];
          float* ar = (float*)aggr + (size_t)idx * 128 + l31 * 4;
          atomicAdd(ar + 0, y4.x); atomicAdd(ar + 1, y4.y);
          atomicAdd(ar + 2, y4.z); atomicAdd(ar + 3, y4.w);
        }
      }
    }
  }
}

extern "C" void kernel_launch(void* const* d_in, const int* in_sizes, int n_in,
                              void* d_out, int out_size, void* d_ws, size_t ws_size,
                              hipStream_t stream) {
  const float* sender_x   = (const float*)d_in[0];
  const float* receiver_x = (const float*)d_in[1];
  const int*   edge_index = (const int*)d_in[2];
  const float* edge_attr  = (const float*)d_in[3];
  const float* We  = (const float*)d_in[4];
  const float* be  = (const float*)d_in[5];
  const float* ge  = (const float*)d_in[6];
  const float* bbe = (const float*)d_in[7];
  const float* Wn  = (const float*)d_in[8];
  const float* bn  = (const float*)d_in[9];
  const float* gn  = (const float*)d_in[10];
  const float* bbn = (const float*)d_in[11];
  const float* Ws  = (const float*)d_in[12];
  const float* bs  = (const float*)d_in[13];
  const float* gs  = (const float*)d_in[14];
  const float* bbs = (const float*)d_in[15];

  const int D  = 128;
  const int NS = in_sizes[0] / D;
  const int NR = in_sizes[1] / D;
  const int E  = in_sizes[2] / 2;

  const int* src = edge_index;
  const int* dst = edge_index + E;

  float* out          = (float*)d_out;
  float* sender_out   = out;
  float* receiver_out = out + (size_t)NS * D;
  float* edge_out     = out + (size_t)(NS + NR) * D;

  // ws layout
  const size_t welems = 128 * 384 + 128 * 256 + 128 * 128;   // 98304
  unsigned short* We_b = (unsigned short*)d_ws;
  unsigned short* Wn_b = We_b + 128 * 384;
  unsigned short* Ws_b = Wn_b + 128 * 256;
  unsigned short* sender_b   = We_b + welems;                 // NS*128
  unsigned short* receiver_b = sender_b + (size_t)NS * D;     // NR*128
  unsigned short* aggrA      = receiver_b + (size_t)NR * D;   // NR*128
  unsigned short* aggrB      = We_b + welems;                 // tier B: right after weights

  const size_t needA = (welems + (size_t)(NS + 2 * NR) * D) * 2;
  const size_t needB = (welems + (size_t)NR * D) * 2;
  const int tier = (ws_size >= needA) ? 0 : (ws_size >= needB ? 1 : 2);

  cvt_weights_kernel<<<(int)((welems + 255) / 256), 256, 0, stream>>>(We, Wn, Ws, We_b);

  const int gridE = (E + 127) / 128;
  const int gridR = (NR + 127) / 128;
  const int gridS = (NS + 127) / 128;

  if (tier == 0) {
    const int n8s = NS * D / 8, n8r = NR * D / 8;
    cvt_rows_kernel<<<(n8s + 255) / 256, 256, 0, stream>>>(sender_x, sender_b, n8s);
    cvt_rows_kernel<<<(n8r + 255) / 256, 256, 0, stream>>>(receiver_x, receiver_b, n8r);
    (void)hipMemsetAsync(aggrA, 0, (size_t)NR * D * 2, stream);

    mlp_rf2_kernel<384, 2, true, true><<<gridE, 256, 0, stream>>>(
        sender_b, src, receiver_b, dst, edge_attr,
        We_b, be, ge, bbe, edge_attr, edge_out, aggrA, dst, E);

    mlp_rf2_kernel<256, 0, true, true><<<gridR, 256, 0, stream>>>(
        receiver_b, nullptr, aggrA, nullptr, nullptr,
        Wn_b, bn, gn, bbn, receiver_x, receiver_out, nullptr, nullptr, NR);

    mlp_rf2_kernel<128, 0, true, false><<<gridS, 256, 0, stream>>>(
        sender_b, nullptr, nullptr, nullptr, nullptr,
        Ws_b, bs, gs, bbs, sender_x, sender_out, nullptr, nullptr, NS);
  } else if (tier == 1) {
    (void)hipMemsetAsync(aggrB, 0, (size_t)NR * D * 2, stream);

    mlp_rf2_kernel<384, 2, false, false><<<gridE, 256, 0, stream>>>(
        sender_x, src, receiver_x, dst, edge_attr,
        We_b, be, ge, bbe, edge_attr, edge_out, aggrB, dst, E);

    mlp_rf2_kernel<256, 0, false, true><<<gridR, 256, 0, stream>>>(
        receiver_x, nullptr, aggrB, nullptr, nullptr,
        Wn_b, bn, gn, bbn, receiver_x, receiver_out, nullptr, nullptr, NR);

    mlp_rf2_kernel<128, 0, false, false><<<gridS, 256, 0, stream>>>(
        sender_x, nullptr, nullptr, nullptr, nullptr,
        Ws_b, bs, gs, bbs, sender_x, sender_out, nullptr, nullptr, NS);
  } else {
    (void)hipMemsetAsync(receiver_out, 0, (size_t)NR * D * sizeof(float), stream);

    mlp_rf2_kernel<384, 1, false, false><<<gridE, 256, 0, stream>>>(
        sender_x, src, receiver_x, dst, edge_attr,
        We_b, be, ge, bbe, edge_attr, edge_out, receiver_out, dst, E);

    mlp_rf2_kernel<256, 0, false, false><<<gridR, 256, 0, stream>>>(
        receiver_x, nullptr, receiver_out, nullptr, nullptr,
        Wn_b, bn, gn, bbn, receiver_x, receiver_out, nullptr, nullptr, NR);

    mlp_rf2_kernel<128, 0, false, false><<<gridS, 256, 0, stream>>>(
        sender_x, nullptr, nullptr, nullptr, nullptr,
        Ws_b, bs, gs, bbs, sender_x, sender_out, nullptr, nullptr, NS);
  }
}